// Round 7
// baseline (69.180 us; speedup 1.0000x reference)
//
#include <hip/hip_runtime.h>

#define NK 512
#define NC 256
#define NH 200
#define NW 200
#define PLANE (NH * NW)
#define RSCALE 0.0625f
#define GC 4                 // channels per block
#define HGC 2                // pairing (ch, ch+2) per thread
#define MAXROWS 32           // max distinct sample rows per roi (span<=31 incl +1)
#define XROW (MAXROWS * 11)  // 352 xdot slots per channel
#define NPAIRA (HGC * XROW)  // 704 max phase-A pair tasks
#define NPAIRB (HGC * 121)   // 242 phase-B pair tasks

// One block per (roi k, 4-channel group). 512 threads.
// XCD-affinity mapping: dispatch round-robins blockIdx across 8 XCDs (blk%8).
// xcd = blk&7, j = blk>>3, k = j&511 (fast), cg = (j>>9)*8 + xcd.
// Each XCD pass (one cg over 512 rois) touches 4 ch x 4 batches x 160 KB
// = 2.56 MB < 4 MB per-XCD L2 -> the ~3x cross-roi re-reads all hit L2,
// independent of roi order. Each plane is fetched from HBM/L3 once per pass.
// Phase 0: 22 threads build per-bin tables.
// Phase A: separable x-pass: xdot[ch][row][pw] = dot4(feat row window, W[pw]).
// Phase B: pooled bin = sum_r wy[r]*xdot[row_r][pw].
// Phase C: 100 threads 3x3/stride2 max-pool -> out, contiguous 100 floats.
__global__ __launch_bounds__(512) void roi_align_maxpool(
    const float* __restrict__ feat,   // (B, C, H, W) f32
    const float* __restrict__ rois,   // (K, 5)
    float* __restrict__ out)          // (K, C, 5, 5)
{
    __shared__ float s_xdot[GC][XROW];   // 5632 B
    __shared__ float s_pool[GC][121];    // 1936 B
    __shared__ int   s_xb[11];           // absolute base col of 4-col window
    __shared__ float s_W [11][4];        // combined x-weights (validity folded)
    __shared__ int   s_yrel[11][4];      // (row - ymin) * 11  (xdot row stride)
    __shared__ float s_wy[11][4];        // 0.25 * vy * (hy|ly)

    const int blk = blockIdx.x;
    const int xcd = blk & 7;             // dispatch: blk % 8 -> XCD id
    const int j   = blk >> 3;
    const int k   = j & (NK - 1);        // roi, fast within an XCD's stream
    const int cg  = ((j >> 9) << 3) | xcd;   // channel-group pinned to this XCD
    const int t   = threadIdx.x;

    const float r0  = rois[k * 5 + 0];
    const float rx1 = rois[k * 5 + 1] * RSCALE;
    const float ry1 = rois[k * 5 + 2] * RSCALE;
    const float rx2 = rois[k * 5 + 3] * RSCALE;
    const float ry2 = rois[k * 5 + 4] * RSCALE;
    const int   b   = (int)r0;
    const float bin_w = fmaxf(rx2 - rx1, 1.0f) / 11.0f;
    const float bin_h = fmaxf(ry2 - ry1, 1.0f) / 11.0f;

    // Uniform ymin/ymax: rows are monotone in (ph, sub); expressions match
    // phase 0 bitwise (same order: start + (p + g)*bs, clamp, floor).
    float cy0 = ry1 + (0.0f + 0.25f) * bin_h;
    cy0 = fminf(fmaxf(cy0, 0.0f), (float)(NH - 1));
    const int ymin = (int)floorf(cy0);
    float cyL = ry1 + (10.0f + 0.75f) * bin_h;
    cyL = fminf(fmaxf(cyL, 0.0f), (float)(NH - 1));
    const int ymax = min((int)floorf(cyL) + 1, NH - 1);
    const int nrows = ymax - ymin + 1;   // 2..32

    if (t < 22) {
        const int d = t / 11;            // 0 = x, 1 = y
        const int pbin = t % 11;
        const float start = d ? ry1 : rx1;
        const float bs    = d ? bin_h : bin_w;
        const int   lim   = d ? NH : NW;
        const float p = (float)pbin;
        float cv0 = start + (p + 0.25f) * bs;   // (0+0.5)/2
        float cv1 = start + (p + 0.75f) * bs;   // (1+0.5)/2
        const float va0 = (cv0 > -1.0f && cv0 < (float)lim) ? 1.0f : 0.0f;
        const float va1 = (cv1 > -1.0f && cv1 < (float)lim) ? 1.0f : 0.0f;
        cv0 = fminf(fmaxf(cv0, 0.0f), (float)(lim - 1));
        cv1 = fminf(fmaxf(cv1, 0.0f), (float)(lim - 1));
        const int lo0 = (int)floorf(cv0);
        const int lo1 = (int)floorf(cv1);
        const int hi0 = min(lo0 + 1, lim - 1);
        const int hi1 = min(lo1 + 1, lim - 1);
        const float fr0 = cv0 - (float)lo0;
        const float fr1 = cv1 - (float)lo1;
        if (d == 0) {
            const int xb = min(lo0, NW - 4);    // 4-col window base (lo1<=lo0+2)
            s_xb[pbin] = xb;
            s_W[pbin][0] = 0.0f; s_W[pbin][1] = 0.0f;
            s_W[pbin][2] = 0.0f; s_W[pbin][3] = 0.0f;
            s_W[pbin][lo0 - xb] += va0 * (1.0f - fr0);
            s_W[pbin][hi0 - xb] += va0 * fr0;
            s_W[pbin][lo1 - xb] += va1 * (1.0f - fr1);
            s_W[pbin][hi1 - xb] += va1 * fr1;
        } else {
            s_yrel[pbin][0] = (lo0 - ymin) * 11;
            s_yrel[pbin][1] = (hi0 - ymin) * 11;
            s_yrel[pbin][2] = (lo1 - ymin) * 11;
            s_yrel[pbin][3] = (hi1 - ymin) * 11;
            s_wy[pbin][0] = 0.25f * va0 * (1.0f - fr0);
            s_wy[pbin][1] = 0.25f * va0 * fr0;
            s_wy[pbin][2] = 0.25f * va1 * (1.0f - fr1);
            s_wy[pbin][3] = 0.25f * va1 * fr1;
        }
    }
    __syncthreads();

    // Phase A: xdot for every needed (ch-pair, row, pw). 704 slots, 2 iters.
    {
        const float* fbase = feat + (size_t)(b * NC + cg * GC) * PLANE;
        #pragma unroll
        for (int i = 0; i < 2; ++i) {
            const int q = t + 512 * i;
            if (q < NPAIRA) {                       // i==0 always true
                const int ch2 = q / XROW;           // 0..1 -> channels ch2, ch2+2
                const int rem = q - ch2 * XROW;
                const int rel = rem / 11;
                const int pw  = rem - rel * 11;
                if (rel < nrows) {
                    const int    xb = s_xb[pw];
                    const float4 W  = *(const float4*)s_W[pw];
                    const float* p0 = fbase + (size_t)ch2 * PLANE + (ymin + rel) * NW + xb;
                    const float4 v0 = *(const float4*)p0;               // ch = ch2
                    const float4 v1 = *(const float4*)(p0 + 2 * PLANE); // ch = ch2+2
                    float d0 = v0.x * W.x; d0 = fmaf(v0.y, W.y, d0); d0 = fmaf(v0.z, W.z, d0); d0 = fmaf(v0.w, W.w, d0);
                    float d1 = v1.x * W.x; d1 = fmaf(v1.y, W.y, d1); d1 = fmaf(v1.z, W.z, d1); d1 = fmaf(v1.w, W.w, d1);
                    s_xdot[ch2    ][rem] = d0;
                    s_xdot[ch2 + 2][rem] = d1;
                }
            }
        }
    }
    __syncthreads();

    // Phase B: combine 4 xdots per bin (pairing ch, ch+2)
    if (t < NPAIRB) {
        const int ch2 = t / 121;
        const int bin = t - ch2 * 121;
        const int ph  = bin / 11;
        const int pw  = bin - ph * 11;
        const int4   yr = *(const int4*)s_yrel[ph];
        const float4 wy = *(const float4*)s_wy[ph];
        const float* xd0 = &s_xdot[ch2    ][pw];
        const float* xd1 = &s_xdot[ch2 + 2][pw];
        float b0 = wy.x * xd0[yr.x];
        b0 = fmaf(wy.y, xd0[yr.y], b0);
        b0 = fmaf(wy.z, xd0[yr.z], b0);
        b0 = fmaf(wy.w, xd0[yr.w], b0);
        float b1 = wy.x * xd1[yr.x];
        b1 = fmaf(wy.y, xd1[yr.y], b1);
        b1 = fmaf(wy.z, xd1[yr.z], b1);
        b1 = fmaf(wy.w, xd1[yr.w], b1);
        s_pool[ch2    ][bin] = b0;   // 0.25 mean folded into wy
        s_pool[ch2 + 2][bin] = b1;
    }
    __syncthreads();

    // Phase C: 3x3/stride2 max-pool, contiguous 100-float store per block
    if (t < GC * 25) {
        const int ch = t / 25;
        const int r  = t % 25;
        const int oh = r / 5, ow = r % 5;
        float m = -INFINITY;
        #pragma unroll
        for (int dy = 0; dy < 3; ++dy)
            #pragma unroll
            for (int dx = 0; dx < 3; ++dx)
                m = fmaxf(m, s_pool[ch][(2 * oh + dy) * 11 + (2 * ow + dx)]);
        out[((size_t)k * NC + cg * GC) * 25 + t] = m;
    }
}

extern "C" void kernel_launch(void* const* d_in, const int* in_sizes, int n_in,
                              void* d_out, int out_size, void* d_ws, size_t ws_size,
                              hipStream_t stream) {
    const float* feat = (const float*)d_in[0];   // (4, 256, 200, 200) f32
    const float* rois = (const float*)d_in[1];   // (512, 5) f32
    float* out = (float*)d_out;                  // (512, 256, 5, 5) f32

    const int nblocks = NK * (NC / GC);          // 32768
    roi_align_maxpool<<<nblocks, 512, 0, stream>>>(feat, rois, out);
}

// Round 8
// 41.927 us; speedup vs baseline: 1.6500x; 1.6500x over previous
//
#include <hip/hip_runtime.h>

#define NK 512
#define NC 256
#define NH 200
#define NW 200
#define PLANE (NH * NW)
#define RSCALE 0.0625f
#define GC 8                 // channels per block
#define HGC 4                // pairing (ch, ch+4) per thread
#define XROW 352             // 32 rows * 11 pw xdot slots per channel
#define NT 256               // threads per block

// One block per (roi k, 8-channel group), 256 threads, XCD-pinned mapping
// (xcd = blk&7 matches dispatch round-robin; cg = local*8+xcd so each
// channel-group's planes are owned by ONE XCD's L2 -- R6's 17% win).
// Overhead cuts vs R6: 256 threads (8 blocks/CU), roi preamble computed by
// t<22 only ({ymin,nrows,b} LDS-broadcast), phase-A task space [rel][ch4][pw]
// sized nrows*44 at runtime (no discarded slots), grid-stride phases.
__global__ __launch_bounds__(NT) void roi_align_maxpool(
    const float* __restrict__ feat,   // (B, C, H, W) f32
    const float* __restrict__ rois,   // (K, 5)
    float* __restrict__ out)          // (K, C, 5, 5)
{
    __shared__ float s_xdot[GC][XROW];   // 11264 B
    __shared__ float s_pool[GC][121];    // 3872 B
    __shared__ int   s_xb[11];           // absolute base col of 4-col window
    __shared__ float s_W [11][4];        // combined x-weights (validity folded)
    __shared__ int   s_yrel[11][4];      // (row - ymin) * 11  (xdot row stride)
    __shared__ float s_wy[11][4];        // 0.25 * vy * (hy|ly)
    __shared__ int   s_meta[3];          // {ymin, nrows, b}

    const int blk = blockIdx.x;
    const int xcd = blk & 7;             // dispatch: blk % 8 -> XCD id
    const int j   = blk >> 3;
    const int k   = j & (NK - 1);        // roi, fast within an XCD's stream
    const int cg  = ((j >> 9) << 3) | xcd;   // channel-group pinned to this XCD
    const int t   = threadIdx.x;

    if (t < 22) {
        const float rx1 = rois[k * 5 + 1] * RSCALE;
        const float ry1 = rois[k * 5 + 2] * RSCALE;
        const float rx2 = rois[k * 5 + 3] * RSCALE;
        const float ry2 = rois[k * 5 + 4] * RSCALE;
        const float bin_w = fmaxf(rx2 - rx1, 1.0f) / 11.0f;
        const float bin_h = fmaxf(ry2 - ry1, 1.0f) / 11.0f;

        const int d = t / 11;            // 0 = x, 1 = y
        const int pbin = t % 11;
        const float start = d ? ry1 : rx1;
        const float bs    = d ? bin_h : bin_w;
        const int   lim   = d ? NH : NW;
        const float p = (float)pbin;
        // sub-sample coords, same expression order as reference
        float cv0 = start + (p + 0.25f) * bs;   // (0+0.5)/2
        float cv1 = start + (p + 0.75f) * bs;   // (1+0.5)/2
        const float va0 = (cv0 > -1.0f && cv0 < (float)lim) ? 1.0f : 0.0f;
        const float va1 = (cv1 > -1.0f && cv1 < (float)lim) ? 1.0f : 0.0f;
        cv0 = fminf(fmaxf(cv0, 0.0f), (float)(lim - 1));
        cv1 = fminf(fmaxf(cv1, 0.0f), (float)(lim - 1));
        const int lo0 = (int)floorf(cv0);
        const int lo1 = (int)floorf(cv1);
        const int hi0 = min(lo0 + 1, lim - 1);
        const int hi1 = min(lo1 + 1, lim - 1);
        const float fr0 = cv0 - (float)lo0;
        const float fr1 = cv1 - (float)lo1;
        if (d == 0) {
            const int xb = min(lo0, NW - 4);    // 4-col window base (lo1<=lo0+2)
            s_xb[pbin] = xb;
            s_W[pbin][0] = 0.0f; s_W[pbin][1] = 0.0f;
            s_W[pbin][2] = 0.0f; s_W[pbin][3] = 0.0f;
            s_W[pbin][lo0 - xb] += va0 * (1.0f - fr0);
            s_W[pbin][hi0 - xb] += va0 * fr0;
            s_W[pbin][lo1 - xb] += va1 * (1.0f - fr1);
            s_W[pbin][hi1 - xb] += va1 * fr1;
            if (pbin == 0) {
                // y-extent: rows monotone in (ph,sub); min row = lo(ph=0,s=0),
                // max row = hi(ph=10,s=1). Same expr order as y-table thread.
                float cy0 = ry1 + (0.0f + 0.25f) * bin_h;
                cy0 = fminf(fmaxf(cy0, 0.0f), (float)(NH - 1));
                const int ymin = (int)floorf(cy0);
                float cyL = ry1 + (10.0f + 0.75f) * bin_h;
                cyL = fminf(fmaxf(cyL, 0.0f), (float)(NH - 1));
                const int ymax = min((int)floorf(cyL) + 1, NH - 1);
                s_meta[0] = ymin;
                s_meta[1] = ymax - ymin + 1;    // nrows in 2..32
                s_meta[2] = (int)rois[k * 5 + 0];
            }
        } else {
            // ymin recomputed here identically (cheap; avoids ordering issues)
            float cy0 = ry1 + (0.0f + 0.25f) * bin_h;
            cy0 = fminf(fmaxf(cy0, 0.0f), (float)(NH - 1));
            const int ymin = (int)floorf(cy0);
            s_yrel[pbin][0] = (lo0 - ymin) * 11;
            s_yrel[pbin][1] = (hi0 - ymin) * 11;
            s_yrel[pbin][2] = (lo1 - ymin) * 11;
            s_yrel[pbin][3] = (hi1 - ymin) * 11;
            s_wy[pbin][0] = 0.25f * va0 * (1.0f - fr0);
            s_wy[pbin][1] = 0.25f * va0 * fr0;
            s_wy[pbin][2] = 0.25f * va1 * (1.0f - fr1);
            s_wy[pbin][3] = 0.25f * va1 * fr1;
        }
    }
    __syncthreads();

    // Phase A: xdot[ch][rel*11+pw] = dot4(feat row window, W[pw]).
    // Task space q = rel*44 + ch4*11 + pw, bound nrows*44 (every slot useful).
    {
        const int ymin  = s_meta[0];
        const int ntask = s_meta[1] * (HGC * 11);
        const int b     = s_meta[2];
        const float* fbase = feat + (size_t)(b * NC + cg * GC) * PLANE;
        for (int q = t; q < ntask; q += NT) {
            const int rel = q / 44;
            const int i44 = q - rel * 44;
            const int ch4 = i44 / 11;
            const int pw  = i44 - ch4 * 11;
            const int    xb = s_xb[pw];
            const float4 W  = *(const float4*)s_W[pw];
            const float* p0 = fbase + (size_t)ch4 * PLANE + (ymin + rel) * NW + xb;
            const float4 v0 = *(const float4*)p0;               // ch = ch4
            const float4 v1 = *(const float4*)(p0 + 4 * PLANE); // ch = ch4+4
            float d0 = v0.x * W.x; d0 = fmaf(v0.y, W.y, d0); d0 = fmaf(v0.z, W.z, d0); d0 = fmaf(v0.w, W.w, d0);
            float d1 = v1.x * W.x; d1 = fmaf(v1.y, W.y, d1); d1 = fmaf(v1.z, W.z, d1); d1 = fmaf(v1.w, W.w, d1);
            const int slot = rel * 11 + pw;
            s_xdot[ch4    ][slot] = d0;
            s_xdot[ch4 + 4][slot] = d1;
        }
    }
    __syncthreads();

    // Phase B: pooled bin = sum_r wy[r] * xdot[row_r][pw]  (pairing ch, ch+4)
    for (int q = t; q < HGC * 121; q += NT) {
        const int ch4 = q / 121;
        const int bin = q - ch4 * 121;
        const int ph  = bin / 11;
        const int pw  = bin - ph * 11;
        const int4   yr = *(const int4*)s_yrel[ph];
        const float4 wy = *(const float4*)s_wy[ph];
        const float* xd0 = &s_xdot[ch4    ][pw];
        const float* xd1 = &s_xdot[ch4 + 4][pw];
        float b0 = wy.x * xd0[yr.x];
        b0 = fmaf(wy.y, xd0[yr.y], b0);
        b0 = fmaf(wy.z, xd0[yr.z], b0);
        b0 = fmaf(wy.w, xd0[yr.w], b0);
        float b1 = wy.x * xd1[yr.x];
        b1 = fmaf(wy.y, xd1[yr.y], b1);
        b1 = fmaf(wy.z, xd1[yr.z], b1);
        b1 = fmaf(wy.w, xd1[yr.w], b1);
        s_pool[ch4    ][bin] = b0;   // 0.25 mean folded into wy
        s_pool[ch4 + 4][bin] = b1;
    }
    __syncthreads();

    // Phase C: 3x3/stride2 max-pool, contiguous 200-float store per block
    if (t < GC * 25) {
        const int ch = t / 25;
        const int r  = t % 25;
        const int oh = r / 5, ow = r % 5;
        float m = -INFINITY;
        #pragma unroll
        for (int dy = 0; dy < 3; ++dy)
            #pragma unroll
            for (int dx = 0; dx < 3; ++dx)
                m = fmaxf(m, s_pool[ch][(2 * oh + dy) * 11 + (2 * ow + dx)]);
        out[((size_t)k * NC + cg * GC) * 25 + t] = m;
    }
}

extern "C" void kernel_launch(void* const* d_in, const int* in_sizes, int n_in,
                              void* d_out, int out_size, void* d_ws, size_t ws_size,
                              hipStream_t stream) {
    const float* feat = (const float*)d_in[0];   // (4, 256, 200, 200) f32
    const float* rois = (const float*)d_in[1];   // (512, 5) f32
    float* out = (float*)d_out;                  // (512, 256, 5, 5) f32

    const int nblocks = NK * (NC / GC);          // 16384
    roi_align_maxpool<<<nblocks, NT, 0, stream>>>(feat, rois, out);
}

// Round 9
// 41.189 us; speedup vs baseline: 1.6796x; 1.0179x over previous
//
#include <hip/hip_runtime.h>

#define NK 512
#define NC 256
#define NH 200
#define NW 200
#define PLANE (NH * NW)
#define RSCALE 0.0625f
#define GC 4                 // channels per block
#define HGC 2                // pairing (ch, ch+2) per thread
#define XROW 352             // 32 rows * 11 pw xdot slots per channel
#define NT 128               // threads per block (2 waves)

// One block per (roi k, 4-channel group), 128 threads, XCD-pinned mapping.
// xcd = blk&7 (dispatch round-robin), j = blk>>3, k = j&511 (fast),
// cg = (j>>9)*8 + xcd  -> each 4-channel group's planes owned by ONE XCD.
// Per-XCD pass working set: 4 ch x 4 batches x 160 KB = 2.56 MB < 4 MB L2
// (R7's fetch collapse), at R8's total thread count (32768 x 128 = R8's
// 16384 x 256) so instruction overhead stays at R8's level.
// Phase 0: t<22 builds tables; others wait (broadcast {ymin,nrows,b} via LDS).
// Phase A: xdot[ch][rel*11+pw] = dot4(feat row window, W[pw]); nrows*22 tasks.
// Phase B: pooled bin = sum_r wy[r]*xdot[row_r][pw]; 242 pair tasks.
// Phase C: 100 threads 3x3/stride2 max-pool -> contiguous 100-float store.
__global__ __launch_bounds__(NT) void roi_align_maxpool(
    const float* __restrict__ feat,   // (B, C, H, W) f32
    const float* __restrict__ rois,   // (K, 5)
    float* __restrict__ out)          // (K, C, 5, 5)
{
    __shared__ float s_xdot[GC][XROW];   // 5632 B
    __shared__ float s_pool[GC][121];    // 1936 B
    __shared__ int   s_xb[11];           // absolute base col of 4-col window
    __shared__ float s_W [11][4];        // combined x-weights (validity folded)
    __shared__ int   s_yrel[11][4];      // (row - ymin) * 11  (xdot row stride)
    __shared__ float s_wy[11][4];        // 0.25 * vy * (hy|ly)
    __shared__ int   s_meta[3];          // {ymin, nrows, b}

    const int blk = blockIdx.x;
    const int xcd = blk & 7;             // dispatch: blk % 8 -> XCD id
    const int j   = blk >> 3;
    const int k   = j & (NK - 1);        // roi, fast within an XCD's stream
    const int cg  = ((j >> 9) << 3) | xcd;   // channel-group pinned to this XCD
    const int t   = threadIdx.x;

    if (t < 22) {
        const float rx1 = rois[k * 5 + 1] * RSCALE;
        const float ry1 = rois[k * 5 + 2] * RSCALE;
        const float rx2 = rois[k * 5 + 3] * RSCALE;
        const float ry2 = rois[k * 5 + 4] * RSCALE;
        const float bin_w = fmaxf(rx2 - rx1, 1.0f) / 11.0f;
        const float bin_h = fmaxf(ry2 - ry1, 1.0f) / 11.0f;

        const int d = t / 11;            // 0 = x, 1 = y
        const int pbin = t % 11;
        const float start = d ? ry1 : rx1;
        const float bs    = d ? bin_h : bin_w;
        const int   lim   = d ? NH : NW;
        const float p = (float)pbin;
        // sub-sample coords, same expression order as reference
        float cv0 = start + (p + 0.25f) * bs;   // (0+0.5)/2
        float cv1 = start + (p + 0.75f) * bs;   // (1+0.5)/2
        const float va0 = (cv0 > -1.0f && cv0 < (float)lim) ? 1.0f : 0.0f;
        const float va1 = (cv1 > -1.0f && cv1 < (float)lim) ? 1.0f : 0.0f;
        cv0 = fminf(fmaxf(cv0, 0.0f), (float)(lim - 1));
        cv1 = fminf(fmaxf(cv1, 0.0f), (float)(lim - 1));
        const int lo0 = (int)floorf(cv0);
        const int lo1 = (int)floorf(cv1);
        const int hi0 = min(lo0 + 1, lim - 1);
        const int hi1 = min(lo1 + 1, lim - 1);
        const float fr0 = cv0 - (float)lo0;
        const float fr1 = cv1 - (float)lo1;
        if (d == 0) {
            const int xb = min(lo0, NW - 4);    // 4-col window base (lo1<=lo0+2)
            s_xb[pbin] = xb;
            s_W[pbin][0] = 0.0f; s_W[pbin][1] = 0.0f;
            s_W[pbin][2] = 0.0f; s_W[pbin][3] = 0.0f;
            s_W[pbin][lo0 - xb] += va0 * (1.0f - fr0);
            s_W[pbin][hi0 - xb] += va0 * fr0;
            s_W[pbin][lo1 - xb] += va1 * (1.0f - fr1);
            s_W[pbin][hi1 - xb] += va1 * fr1;
            if (pbin == 0) {
                // y-extent: rows monotone in (ph,sub); min row = lo(0,0),
                // max row = hi(10,1). Same expr order as y-table threads.
                float cy0 = ry1 + (0.0f + 0.25f) * bin_h;
                cy0 = fminf(fmaxf(cy0, 0.0f), (float)(NH - 1));
                const int ymin = (int)floorf(cy0);
                float cyL = ry1 + (10.0f + 0.75f) * bin_h;
                cyL = fminf(fmaxf(cyL, 0.0f), (float)(NH - 1));
                const int ymax = min((int)floorf(cyL) + 1, NH - 1);
                s_meta[0] = ymin;
                s_meta[1] = ymax - ymin + 1;    // nrows in 2..32
                s_meta[2] = (int)rois[k * 5 + 0];
            }
        } else {
            // ymin recomputed identically (avoids cross-thread ordering)
            float cy0 = ry1 + (0.0f + 0.25f) * bin_h;
            cy0 = fminf(fmaxf(cy0, 0.0f), (float)(NH - 1));
            const int ymin = (int)floorf(cy0);
            s_yrel[pbin][0] = (lo0 - ymin) * 11;
            s_yrel[pbin][1] = (hi0 - ymin) * 11;
            s_yrel[pbin][2] = (lo1 - ymin) * 11;
            s_yrel[pbin][3] = (hi1 - ymin) * 11;
            s_wy[pbin][0] = 0.25f * va0 * (1.0f - fr0);
            s_wy[pbin][1] = 0.25f * va0 * fr0;
            s_wy[pbin][2] = 0.25f * va1 * (1.0f - fr1);
            s_wy[pbin][3] = 0.25f * va1 * fr1;
        }
    }
    __syncthreads();

    // Phase A: xdot[ch][rel*11+pw] = dot4(feat row window, W[pw]).
    // Task q = rel*22 + ch2*11 + pw, bound nrows*22 (every slot useful).
    {
        const int ymin  = s_meta[0];
        const int ntask = s_meta[1] * (HGC * 11);
        const int b     = s_meta[2];
        const float* fbase = feat + (size_t)(b * NC + cg * GC) * PLANE;
        for (int q = t; q < ntask; q += NT) {
            const int rel = q / 22;
            const int i22 = q - rel * 22;
            const int ch2 = i22 / 11;
            const int pw  = i22 - ch2 * 11;
            const int    xb = s_xb[pw];
            const float4 W  = *(const float4*)s_W[pw];
            const float* p0 = fbase + (size_t)ch2 * PLANE + (ymin + rel) * NW + xb;
            const float4 v0 = *(const float4*)p0;               // ch = ch2
            const float4 v1 = *(const float4*)(p0 + 2 * PLANE); // ch = ch2+2
            float d0 = v0.x * W.x; d0 = fmaf(v0.y, W.y, d0); d0 = fmaf(v0.z, W.z, d0); d0 = fmaf(v0.w, W.w, d0);
            float d1 = v1.x * W.x; d1 = fmaf(v1.y, W.y, d1); d1 = fmaf(v1.z, W.z, d1); d1 = fmaf(v1.w, W.w, d1);
            const int slot = rel * 11 + pw;
            s_xdot[ch2    ][slot] = d0;
            s_xdot[ch2 + 2][slot] = d1;
        }
    }
    __syncthreads();

    // Phase B: pooled bin = sum_r wy[r] * xdot[row_r][pw]  (pairing ch, ch+2)
    for (int q = t; q < HGC * 121; q += NT) {
        const int ch2 = q / 121;
        const int bin = q - ch2 * 121;
        const int ph  = bin / 11;
        const int pw  = bin - ph * 11;
        const int4   yr = *(const int4*)s_yrel[ph];
        const float4 wy = *(const float4*)s_wy[ph];
        const float* xd0 = &s_xdot[ch2    ][pw];
        const float* xd1 = &s_xdot[ch2 + 2][pw];
        float b0 = wy.x * xd0[yr.x];
        b0 = fmaf(wy.y, xd0[yr.y], b0);
        b0 = fmaf(wy.z, xd0[yr.z], b0);
        b0 = fmaf(wy.w, xd0[yr.w], b0);
        float b1 = wy.x * xd1[yr.x];
        b1 = fmaf(wy.y, xd1[yr.y], b1);
        b1 = fmaf(wy.z, xd1[yr.z], b1);
        b1 = fmaf(wy.w, xd1[yr.w], b1);
        s_pool[ch2    ][bin] = b0;   // 0.25 mean folded into wy
        s_pool[ch2 + 2][bin] = b1;
    }
    __syncthreads();

    // Phase C: 3x3/stride2 max-pool, contiguous 100-float store per block
    if (t < GC * 25) {
        const int ch = t / 25;
        const int r  = t % 25;
        const int oh = r / 5, ow = r % 5;
        float m = -INFINITY;
        #pragma unroll
        for (int dy = 0; dy < 3; ++dy)
            #pragma unroll
            for (int dx = 0; dx < 3; ++dx)
                m = fmaxf(m, s_pool[ch][(2 * oh + dy) * 11 + (2 * ow + dx)]);
        out[((size_t)k * NC + cg * GC) * 25 + t] = m;
    }
}

extern "C" void kernel_launch(void* const* d_in, const int* in_sizes, int n_in,
                              void* d_out, int out_size, void* d_ws, size_t ws_size,
                              hipStream_t stream) {
    const float* feat = (const float*)d_in[0];   // (4, 256, 200, 200) f32
    const float* rois = (const float*)d_in[1];   // (512, 5) f32
    float* out = (float*)d_out;                  // (512, 256, 5, 5) f32

    const int nblocks = NK * (NC / GC);          // 32768
    roi_align_maxpool<<<nblocks, NT, 0, stream>>>(feat, rois, out);
}